// Round 5
// baseline (331.469 us; speedup 1.0000x reference)
//
#include <hip/hip_runtime.h>
#include <hip/hip_bf16.h>

typedef __hip_bfloat16 bf16;
typedef __attribute__((ext_vector_type(8))) short short8;
typedef __attribute__((ext_vector_type(4))) float floatx4;
typedef unsigned long long u64;

#define NVP 10242
#define NV  40962
#define NF  81920
#define FPF 2   // faces per wave in k_facegrad

__device__ __forceinline__ unsigned short f2bfbits(float f) {
    bf16 h = __float2bfloat16(f);
    return __builtin_bit_cast(unsigned short, h);
}
// fp8 e4m3 (OCP on gfx950)
__device__ __forceinline__ unsigned short pk_fp8(float a, float b) {
    int p = __builtin_amdgcn_cvt_pk_fp8_f32(a, b, 0, false);
    return (unsigned short)(p & 0xffff);
}
__device__ __forceinline__ unsigned char one_fp8(float a) {
    int p = __builtin_amdgcn_cvt_pk_fp8_f32(a, 0.f, 0, false);
    return (unsigned char)(p & 0xff);
}
__device__ __forceinline__ float f8s0(unsigned int u){return __builtin_amdgcn_cvt_f32_fp8(u,0);}
__device__ __forceinline__ float f8s1(unsigned int u){return __builtin_amdgcn_cvt_f32_fp8(u,1);}
__device__ __forceinline__ float f8s2(unsigned int u){return __builtin_amdgcn_cvt_f32_fp8(u,2);}
__device__ __forceinline__ float f8s3(unsigned int u){return __builtin_amdgcn_cvt_f32_fp8(u,3);}
__device__ __forceinline__ void unpack8(u64 v, float o[8]) {
    unsigned int lo = (unsigned int)v, hi = (unsigned int)(v >> 32);
    o[0]=f8s0(lo); o[1]=f8s1(lo); o[2]=f8s2(lo); o[3]=f8s3(lo);
    o[4]=f8s0(hi); o[5]=f8s1(hi); o[6]=f8s2(hi); o[7]=f8s3(hi);
}

// ---------------------------------------------------------------------------
// K0 (merged prep): blocks [0,64): coeffsB; [64,384): packG; [384,545): packV.
// Gpk per-face 128 B: dw[0..8] 9 cols | dw[16..24] 9 vals | dw[25..27] EW |
//                     dw[28..30] NS.
// Vpk per-vertex 128 B: dw[0..6] 7 Lcols | dw[8..13] 6 F2Vcols |
//                       dw[16..22] 7 Lvals | dw[24..29] 6 F2Vvals.
// ---------------------------------------------------------------------------
__global__ void k_prep(const float* __restrict__ coeffs,
                       unsigned short* __restrict__ coeffsB,
                       const int* __restrict__ G_cols,
                       const float* __restrict__ G_vals,
                       const float* __restrict__ EW,
                       const float* __restrict__ NS,
                       float* __restrict__ Gpk,
                       const int* __restrict__ L_cols,
                       const float* __restrict__ L_vals,
                       const int* __restrict__ F2V_cols,
                       const float* __restrict__ F2V_vals,
                       float* __restrict__ Vpk) {
    int b = blockIdx.x;
    if (b < 64) {
        int t = b * 256 + threadIdx.x;                 // 0..16383
        int j = t & 7, lane = (t >> 3) & 63, s = t >> 9;
        int ot = s >> 3, kk = s & 7;
        int o  = ot * 16 + (lane & 15);
        int kg = kk * 32 + (lane >> 4) * 8 + j;
        coeffsB[t] = f2bfbits(coeffs[o * 256 + kg]);
    } else if (b < 384) {
        int f = (b - 64) * 256 + threadIdx.x;          // NF/256 = 320 exact
        float r[32];
#pragma unroll
        for (int q = 0; q < 32; ++q) r[q] = 0.f;
#pragma unroll
        for (int d = 0; d < 3; ++d)
#pragma unroll
            for (int j = 0; j < 3; ++j) {
                int idx = (d * NF + f) * 3 + j;
                r[d * 3 + j]      = __int_as_float(G_cols[idx]);
                r[16 + d * 3 + j] = G_vals[idx];
            }
#pragma unroll
        for (int d = 0; d < 3; ++d) {
            r[25 + d] = EW[f * 3 + d];
            r[28 + d] = NS[f * 3 + d];
        }
        float4* dst = (float4*)(Gpk + (size_t)f * 32);
#pragma unroll
        for (int q = 0; q < 8; ++q) dst[q] = ((const float4*)r)[q];
    } else {
        int v = (b - 384) * 256 + threadIdx.x;
        if (v >= NV) return;
        float r[32];
#pragma unroll
        for (int q = 0; q < 32; ++q) r[q] = 0.f;
#pragma unroll
        for (int j = 0; j < 7; ++j) {
            r[j]      = __int_as_float(L_cols[v * 7 + j]);
            r[16 + j] = L_vals[v * 7 + j];
        }
#pragma unroll
        for (int j = 0; j < 6; ++j) {
            r[8 + j]  = __int_as_float(F2V_cols[v * 6 + j]);
            r[24 + j] = F2V_vals[v * 6 + j];
        }
        float4* dst = (float4*)(Vpk + (size_t)v * 32);
#pragma unroll
        for (int q = 0; q < 8; ++q) dst[q] = ((const float4*)r)[q];
    }
}

// ---------------------------------------------------------------------------
// K1: batch-packing transpose. x[b][c][v] fp32 (all 8 b) ->
//   xinp [v][c][b0..7] bf16 (uint4/entry), xin8p [v][c][b0..7] fp8 (u64).
// One gather row is now 512 B serving ALL batches. LDS shuffles (v fast on
// read) -> (c fast on write) for coalescing; u64 elements keep banks 2-way.
// ---------------------------------------------------------------------------
__global__ void __launch_bounds__(256) k_transpose(
    const float* __restrict__ x,
    uint4* __restrict__ xinp, u64* __restrict__ xin8p) {
    __shared__ u64 t8 [32][65];
    __shared__ u64 tbL[32][65];
    __shared__ u64 tbH[32][65];
    int v0 = blockIdx.x * 64;
    int tx = threadIdx.x & 63, ty = threadIdx.x >> 6;  // ty 0..3
    for (int half = 0; half < 2; ++half) {
        if (half) __syncthreads();
#pragma unroll
        for (int r = 0; r < 8; ++r) {
            int c  = ty + r * 4;             // 0..31
            int cg = half * 32 + c;
            int v  = v0 + tx;
            u64 p8 = 0, bL = 0, bH = 0;
#pragma unroll
            for (int b = 0; b < 8; ++b) {
                float val = (v < NVP) ? x[((size_t)b * 64 + cg) * NVP + v] : 1.0f;
                p8 |= (u64)one_fp8(val) << (8 * b);
                u64 bf = (u64)f2bfbits(val);
                if (b < 4) bL |= bf << (16 * b);
                else       bH |= bf << (16 * (b - 4));
            }
            t8[c][tx] = p8; tbL[c][tx] = bL; tbH[c][tx] = bH;
        }
        __syncthreads();
        int cc = threadIdx.x & 31;
        int vq = threadIdx.x >> 5;           // 0..7
#pragma unroll
        for (int it = 0; it < 8; ++it) {
            int v  = vq * 8 + it;            // 0..63
            int vg = v0 + v;
            if (vg < NV) {
                size_t idx = (size_t)vg * 64 + half * 32 + cc;
                xin8p[idx] = t8[cc][v];
                u64 lo = tbL[cc][v], hi = tbH[cc][v];
                xinp[idx] = make_uint4((unsigned)lo, (unsigned)(lo >> 32),
                                       (unsigned)hi, (unsigned)(hi >> 32));
            }
        }
    }
}

// ---------------------------------------------------------------------------
// K2: face gradients, all 8 batches per wave-face. 9 u64 gathers/face (was
// 72 across batch dispatches); sched_barrier(0) forces all gathers in
// flight before math. Output gfip[f][c][b]: (ew|ns) fp8 pair x8 = uint4.
// ---------------------------------------------------------------------------
__global__ void __launch_bounds__(256, 4) k_facegrad(
    const u64* __restrict__ xin8p,
    const float* __restrict__ Gpk,
    uint4* __restrict__ gfip) {
    int w  = __builtin_amdgcn_readfirstlane(threadIdx.x >> 6);
    int c  = threadIdx.x & 63;
    int f0 = (blockIdx.x * 4 + w) * FPF;

    // stage A: scalar col loads
    int gc[FPF][9];
#pragma unroll
    for (int i = 0; i < FPF; ++i) {
        const int* ri = (const int*)(Gpk + (size_t)(f0 + i) * 32);
#pragma unroll
        for (int j = 0; j < 9; ++j) gc[i][j] = ri[j];
    }
    // stage B: all 18 u64 gathers in flight
    u64 xv[FPF][9];
#pragma unroll
    for (int i = 0; i < FPF; ++i)
#pragma unroll
        for (int j = 0; j < 9; ++j)
            xv[i][j] = xin8p[(size_t)gc[i][j] * 64 + c];
    __builtin_amdgcn_sched_barrier(0);
    // stage C: per-batch math + store
#pragma unroll
    for (int i = 0; i < FPF; ++i) {
        const float* rf = Gpk + (size_t)(f0 + i) * 32;
        float g0[8], g1[8], g2[8];
#pragma unroll
        for (int b = 0; b < 8; ++b) { g0[b] = 0.f; g1[b] = 0.f; g2[b] = 0.f; }
#pragma unroll
        for (int j = 0; j < 3; ++j) {
            float fa[8], fb[8], fc_[8];
            unpack8(xv[i][j],     fa);
            unpack8(xv[i][3 + j], fb);
            unpack8(xv[i][6 + j], fc_);
            float va = rf[16 + j], vb = rf[19 + j], vc = rf[22 + j];
#pragma unroll
            for (int b = 0; b < 8; ++b) {
                g0[b] += va * fa[b];
                g1[b] += vb * fb[b];
                g2[b] += vc * fc_[b];
            }
        }
        float e0 = rf[25], e1 = rf[26], e2 = rf[27];
        float n0 = rf[28], n1 = rf[29], n2 = rf[30];
        unsigned int d[4] = {0u, 0u, 0u, 0u};
#pragma unroll
        for (int b = 0; b < 8; ++b) {
            float ew = g0[b] * e0 + g1[b] * e1 + g2[b] * e2;
            float ns = g0[b] * n0 + g1[b] * n1 + g2[b] * n2;
            d[b >> 1] |= (unsigned int)pk_fp8(ew, ns) << ((b & 1) * 16);
        }
        gfip[(size_t)(f0 + i) * 64 + c] = make_uint4(d[0], d[1], d[2], d[3]);
    }
}

// ---------------------------------------------------------------------------
// K3: vertex kernel, all 8 batches per wave-vertex. Block 512 = 8 waves = 8
// vertices; MFMA rows are (v,b) pairs: 64 rows = 4 row-tiles. 14 gathers per
// vertex serve all batches; sched_barrier(0) pins them in flight.
// Phase 2: wave w -> row-tile (w&3), o-tile pair (w>>2)*2+{0,1}.
// ---------------------------------------------------------------------------
__global__ void __launch_bounds__(512, 2) k_vertex(
    const uint4* __restrict__ xinp,
    const u64* __restrict__ xin8p,
    const float* __restrict__ Vpk,
    const uint4* __restrict__ gfip,
    const unsigned short* __restrict__ coeffsB,
    const float* __restrict__ bias,
    float* __restrict__ out) {
    int vb = blockIdx.x * 8;
    __shared__ unsigned short feat[64 * 264];   // 33792 B
    __shared__ float outs[64 * 67];             // 17152 B
    int w    = __builtin_amdgcn_readfirstlane(threadIdx.x >> 6);  // 0..7
    int c    = threadIdx.x & 63;
    int v    = vb + w;
    int vcs  = __builtin_amdgcn_readfirstlane(v < NV ? v : NV - 1);

    // stage A: scalar col loads
    const int* ri = (const int*)(Vpk + (size_t)vcs * 32);
    int lc[7], fc[6];
#pragma unroll
    for (int j = 0; j < 7; ++j) lc[j] = ri[j];
#pragma unroll
    for (int j = 0; j < 6; ++j) fc[j] = ri[8 + j];
    // stage B: 14 wide gathers in flight (serve all 8 batches each)
    uint4 f0q = xinp[(size_t)vcs * 64 + c];
    u64 xl[7];
#pragma unroll
    for (int j = 0; j < 7; ++j) xl[j] = xin8p[(size_t)lc[j] * 64 + c];
    uint4 gq[6];
#pragma unroll
    for (int j = 0; j < 6; ++j) gq[j] = gfip[(size_t)fc[j] * 64 + c];
    __builtin_amdgcn_sched_barrier(0);
    // stage C: per-batch math
    const float* rv = Vpk + (size_t)vcs * 32;
    float lap[8], ew[8], ns[8];
#pragma unroll
    for (int b = 0; b < 8; ++b) { lap[b] = 0.f; ew[b] = 0.f; ns[b] = 0.f; }
#pragma unroll
    for (int j = 0; j < 7; ++j) {
        float xa[8];
        unpack8(xl[j], xa);
        float lv = rv[16 + j];
#pragma unroll
        for (int b = 0; b < 8; ++b) lap[b] += lv * xa[b];
    }
#pragma unroll
    for (int j = 0; j < 6; ++j) {
        float val = rv[24 + j];
        unsigned int q0 = gq[j].x, q1 = gq[j].y, q2 = gq[j].z, q3 = gq[j].w;
        ew[0] += val * f8s0(q0); ns[0] += val * f8s1(q0);
        ew[1] += val * f8s2(q0); ns[1] += val * f8s3(q0);
        ew[2] += val * f8s0(q1); ns[2] += val * f8s1(q1);
        ew[3] += val * f8s2(q1); ns[3] += val * f8s3(q1);
        ew[4] += val * f8s0(q2); ns[4] += val * f8s1(q2);
        ew[5] += val * f8s2(q2); ns[5] += val * f8s3(q2);
        ew[6] += val * f8s0(q3); ns[6] += val * f8s1(q3);
        ew[7] += val * f8s2(q3); ns[7] += val * f8s3(q3);
    }
    unsigned int fd[4] = {f0q.x, f0q.y, f0q.z, f0q.w};
#pragma unroll
    for (int b = 0; b < 8; ++b) {
        unsigned short f0s = (unsigned short)(fd[b >> 1] >> ((b & 1) * 16));
        ushort4 p = make_ushort4(f0s, f2bfbits(lap[b]),
                                 f2bfbits(ew[b]), f2bfbits(ns[b]));
        *(ushort4*)&feat[(w * 8 + b) * 264 + c * 4] = p;
    }
    __syncthreads();

    // ---- phase 2: MFMA. wave w: row-tile rt = w&3, o-tiles (w>>2)*2+{0,1} --
    int m = c & 15, quad = c >> 4;
    int rt = w & 3, ob = (w >> 2) * 2;
    float b0v = bias[ob * 16 + m], b1v = bias[(ob + 1) * 16 + m];
    floatx4 acc0 = {b0v, b0v, b0v, b0v};
    floatx4 acc1 = {b1v, b1v, b1v, b1v};
#pragma unroll
    for (int kk = 0; kk < 8; ++kk) {
        short8 a  = *(const short8*)&feat[(rt * 16 + m) * 264 + kk * 32 + quad * 8];
        short8 f0 = *(const short8*)&coeffsB[((ob * 8 + kk) * 64 + c) * 8];
        short8 f1 = *(const short8*)&coeffsB[(((ob + 1) * 8 + kk) * 64 + c) * 8];
        acc0 = __builtin_amdgcn_mfma_f32_16x16x32_bf16(a, f0, acc0, 0, 0, 0);
        acc1 = __builtin_amdgcn_mfma_f32_16x16x32_bf16(a, f1, acc1, 0, 0, 0);
    }
#pragma unroll
    for (int r = 0; r < 4; ++r) {
        outs[(rt * 16 + quad * 4 + r) * 67 + ob * 16 + m]       = acc0[r];
        outs[(rt * 16 + quad * 4 + r) * 67 + (ob + 1) * 16 + m] = acc1[r];
    }
    __syncthreads();

    // ---- epilogue: out[b][o][vb..vb+7], rows = vloc*8 + b ----
    int vloc = threadIdx.x & 7;
    int g    = threadIdx.x >> 3;   // 0..63 = o
    if (vb + vloc < NV) {
#pragma unroll
        for (int p = 0; p < 8; ++p) {  // p = batch
            out[((size_t)p * 64 + g) * NV + vb + vloc] =
                outs[(vloc * 8 + p) * 67 + g];
        }
    }
}

// ---------------------------------------------------------------------------
extern "C" void kernel_launch(void* const* d_in, const int* in_sizes, int n_in,
                              void* d_out, int out_size, void* d_ws, size_t ws_size,
                              hipStream_t stream) {
    const float* x        = (const float*)d_in[0];
    const int*   G_cols   = (const int*)  d_in[2];
    const float* G_vals   = (const float*)d_in[3];
    const int*   L_cols   = (const int*)  d_in[5];
    const float* L_vals   = (const float*)d_in[6];
    const int*   F2V_cols = (const int*)  d_in[8];
    const float* F2V_vals = (const float*)d_in[9];
    const float* EW       = (const float*)d_in[10];
    const float* NS       = (const float*)d_in[11];
    const float* coeffs   = (const float*)d_in[12];
    const float* bias     = (const float*)d_in[13];
    float* out = (float*)d_out;

    char* ws = (char*)d_ws;
    const size_t gpk_bytes  = (size_t)NF * 128;      // 10.49 MB
    const size_t vpk_bytes  = (size_t)NV * 128;      //  5.24 MB
    const size_t xinp_bytes = (size_t)NV * 64 * 16;  // 41.95 MB
    const size_t x8p_bytes  = (size_t)NV * 64 * 8;   // 20.97 MB
    // gfip = NF*64*16 = 83.89 MB; total = 162,598,144 B (== old nb=8 need)

    unsigned short* coeffsB = (unsigned short*)ws;                    // 32 KB
    float* Gpk   = (float*)(ws + 65536);
    float* Vpk   = (float*)(ws + 65536 + gpk_bytes);
    uint4* xinp  = (uint4*)(ws + 65536 + gpk_bytes + vpk_bytes);
    u64*   xin8p = (u64*)  (ws + 65536 + gpk_bytes + vpk_bytes + xinp_bytes);
    uint4* gfip  = (uint4*)(ws + 65536 + gpk_bytes + vpk_bytes + xinp_bytes
                               + x8p_bytes);

    k_prep<<<545, 256, 0, stream>>>(coeffs, coeffsB, G_cols, G_vals, EW, NS,
                                    Gpk, L_cols, L_vals, F2V_cols, F2V_vals,
                                    Vpk);
    k_transpose<<<641, 256, 0, stream>>>(x, xinp, xin8p);
    k_facegrad<<<NF / (4 * FPF), 256, 0, stream>>>(xin8p, Gpk, gfip);
    k_vertex<<<(NV + 7) / 8, 512, 0, stream>>>(xinp, xin8p, Vpk, gfip,
                                               coeffsB, bias, out);
}